// Round 7
// baseline (100064.667 us; speedup 1.0000x reference)
//
#include <hip/hip_runtime.h>
#include <math.h>

constexpr int Bsz = 256, Tsz = 1024, Isz = 64, Hsz = 256, Osz = 8;
constexpr int NB = 4;      // batch rows per group
constexpr int NG = 4;      // column-split wgs per batch group
constexpr int K  = Hsz + Isz;    // 320
constexpr int RQ_OWN = 16;       // own-slice quads (rows 0..63) in regs
constexpr int RQ_REG = 27;       // total h-row quads in regs (108 rows)
constexpr int LQ     = 37;       // h-row quads in LDS (148 rows); 27*4+37*4 = 256 rows
constexpr int SPIN_CAP = 1 << 16;

#define SCOPE_AGENT __HIP_MEMORY_SCOPE_AGENT

// ---------------- x-projection pre-pass:  xproj[b][t][1024] = x[b,t,:] @ Wx + bias ----
__global__ __launch_bounds__(256) void xproj_kernel(
    const float* __restrict__ x,
    const float* __restrict__ W_f, const float* __restrict__ b_f,
    const float* __restrict__ W_i, const float* __restrict__ b_i,
    const float* __restrict__ W_c, const float* __restrict__ b_c,
    const float* __restrict__ W_o, const float* __restrict__ b_o,
    float* __restrict__ xproj)
{
    __shared__ __align__(16) float xs[32][Isz];   // 32 t-steps x 64 inputs, 8 KB
    const int j  = threadIdx.x;
    const int t0 = blockIdx.x * 32;
    const int b  = blockIdx.y;
    const int cg = blockIdx.z;        // gate 0..3
    const float* Wq = (cg == 0) ? W_f : (cg == 1) ? W_i : (cg == 2) ? W_c : W_o;
    const float* bq = (cg == 0) ? b_f : (cg == 1) ? b_i : (cg == 2) ? b_c : b_o;

    // weights for my column: rows 256..319 of Wq
    float4 w4[16];
    #pragma unroll
    for (int iq = 0; iq < 16; ++iq) {
        w4[iq].x = Wq[(Hsz + iq * 4 + 0) * Hsz + j];
        w4[iq].y = Wq[(Hsz + iq * 4 + 1) * Hsz + j];
        w4[iq].z = Wq[(Hsz + iq * 4 + 2) * Hsz + j];
        w4[iq].w = Wq[(Hsz + iq * 4 + 3) * Hsz + j];
    }
    // stage x tile: 2048 floats, thread j loads floats j*8..j*8+7
    {
        const float* src = x + ((size_t)b * Tsz + t0) * Isz;
        *(float4*)&xs[0][0 + j * 8]     = *(const float4*)&src[j * 8];
        *(float4*)&xs[0][4 + j * 8]     = *(const float4*)&src[j * 8 + 4];
    }
    __syncthreads();

    const float bias = bq[j];
    float* dst = xproj + ((size_t)b * Tsz + t0) * 1024 + cg * 256 + j;
    #pragma unroll 4
    for (int tt = 0; tt < 32; ++tt) {
        float acc = bias;
        #pragma unroll
        for (int iq = 0; iq < 16; ++iq) {
            const float4 v = *(const float4*)&xs[tt][iq * 4];
            acc = fmaf(v.x, w4[iq].x, acc);
            acc = fmaf(v.y, w4[iq].y, acc);
            acc = fmaf(v.z, w4[iq].z, acc);
            acc = fmaf(v.w, w4[iq].w, acc);
        }
        dst[(size_t)tt * 1024] = acc;
    }
}

// ---------------- recurrent kernel ----------------
// XPRE=true: x-projection precomputed (K=256 h-rows only).
// XPRE=false: fallback, x handled in-loop (K=320).
template<bool XPRE>
__global__ __launch_bounds__(256, 1) void lstm_ws_kernel(
    const float* __restrict__ x,
    const float* __restrict__ W_f, const float* __restrict__ b_f,
    const float* __restrict__ W_i, const float* __restrict__ b_i,
    const float* __restrict__ W_c, const float* __restrict__ b_c,
    const float* __restrict__ W_o, const float* __restrict__ b_o,
    const float* __restrict__ W_ho, const float* __restrict__ b_ho,
    float* __restrict__ out, int* __restrict__ cnt, float* __restrict__ Hbuf,
    const float* __restrict__ xproj)
{
    __shared__ __align__(16) float comb[NB][K];          // [h(256) | x(64)] 5120 B
    __shared__ float gat[4][NB][64];                     // 4096 B
    __shared__ __align__(16) float4 WldsQ[LQ][256];      // 151552 B; total 160768 B

    const int j  = threadIdx.x;
    const int g  = blockIdx.x >> 6;
    const int bg = blockIdx.x & 63;
    const int b0 = bg * NB;
    const int q  = j >> 6;
    const int m  = j & 63;
    const int hcol = g * 64 + m;

    const float* Wq  = (q == 0) ? W_f : (q == 1) ? W_i : (q == 2) ? W_c : W_o;
    const float* bqp = (q == 0) ? b_f : (q == 1) ? b_i : (q == 2) ? b_c : b_o;
    const float bias = bqp[hcol];

    // rotated h-row order: o<64 -> own slice row g*64+o ; o>=64 -> ((g+1+((o-64)>>6))&3)*64 + ((o-64)&63)
    const int kb1 = ((g + 1) & 3) * 64, kb2 = ((g + 2) & 3) * 64, kb3 = ((g + 3) & 3) * 64;

    // ---- weight preload: quads 0..26 -> regs, quads 27..63 -> LDS ----
    float4 wR4[RQ_REG];
    #pragma unroll
    for (int qd = 0; qd < RQ_OWN; ++qd) {        // own slice rows 0..63
        const int kbase = g * 64 + qd * 4;
        wR4[qd].x = Wq[(kbase + 0) * Hsz + hcol];
        wR4[qd].y = Wq[(kbase + 1) * Hsz + hcol];
        wR4[qd].z = Wq[(kbase + 2) * Hsz + hcol];
        wR4[qd].w = Wq[(kbase + 3) * Hsz + hcol];
    }
    #pragma unroll
    for (int qd = RQ_OWN; qd < RQ_REG; ++qd) {   // (g+1) slice rows 0..43
        const int kbase = kb1 + (qd - RQ_OWN) * 4;
        wR4[qd].x = Wq[(kbase + 0) * Hsz + hcol];
        wR4[qd].y = Wq[(kbase + 1) * Hsz + hcol];
        wR4[qd].z = Wq[(kbase + 2) * Hsz + hcol];
        wR4[qd].w = Wq[(kbase + 3) * Hsz + hcol];
    }
    for (int rr = 0; rr < LQ; ++rr) {            // rotated rows 108..255
        const int obo = 44 + rr * 4;             // offset past own slice: 44..191
        const int kbase = ((obo >> 6) == 0 ? kb1 : (obo >> 6) == 1 ? kb2 : kb3) + (obo & 63);
        float4 wv;
        wv.x = Wq[(kbase + 0) * Hsz + hcol];
        wv.y = Wq[(kbase + 1) * Hsz + hcol];
        wv.z = Wq[(kbase + 2) * Hsz + hcol];
        wv.w = Wq[(kbase + 3) * Hsz + hcol];
        WldsQ[rr][j] = wv;
    }
    float4 wX4[XPRE ? 1 : 16];
    if constexpr (!XPRE) {
        #pragma unroll
        for (int iq = 0; iq < 16; ++iq) {
            wX4[iq].x = Wq[(Hsz + iq * 4 + 0) * Hsz + hcol];
            wX4[iq].y = Wq[(Hsz + iq * 4 + 1) * Hsz + hcol];
            wX4[iq].z = Wq[(Hsz + iq * 4 + 2) * Hsz + hcol];
            wX4[iq].w = Wq[(Hsz + iq * 4 + 3) * Hsz + hcol];
        }
    }

    // ---- init: h(-1)=0; stage x(0) (fallback only) ----
    #pragma unroll
    for (int b = 0; b < NB; ++b) comb[b][j] = 0.0f;
    if constexpr (!XPRE)
        comb[j >> 6][Hsz + m] = x[((size_t)(b0 + (j >> 6)) * Tsz + 0) * Isz + m];
    float cstate = 0.0f;
    __syncthreads();

    const float* xpbase = XPRE ? (xproj + (size_t)q * 256 + g * 64 + m) : nullptr;
    float xpc[NB];
    if constexpr (XPRE) {
        #pragma unroll
        for (int b = 0; b < NB; ++b)
            xpc[b] = xpbase[((size_t)(b0 + b) * Tsz + 0) * 1024];
    }

    int* mycnt = cnt + bg;

    for (int t = 0; t < Tsz; ++t) {
        float acc[NB];
        #pragma unroll
        for (int b = 0; b < NB; ++b) acc[b] = XPRE ? xpc[b] : bias;

        // ---- phase A: own h slice (+ x in fallback) — before the spin ----
        const int ob = g * 64;
        #pragma unroll
        for (int qd = 0; qd < RQ_OWN; ++qd) {
            const float4 w = wR4[qd];
            #pragma unroll
            for (int b = 0; b < NB; ++b) {
                const float4 v = *(const float4*)&comb[b][ob + qd * 4];
                acc[b] = fmaf(v.x, w.x, acc[b]);
                acc[b] = fmaf(v.y, w.y, acc[b]);
                acc[b] = fmaf(v.z, w.z, acc[b]);
                acc[b] = fmaf(v.w, w.w, acc[b]);
            }
        }
        if constexpr (!XPRE) {
            #pragma unroll
            for (int iq = 0; iq < 16; ++iq) {
                const float4 w = wX4[iq];
                #pragma unroll
                for (int b = 0; b < NB; ++b) {
                    const float4 v = *(const float4*)&comb[b][Hsz + iq * 4];
                    acc[b] = fmaf(v.x, w.x, acc[b]);
                    acc[b] = fmaf(v.y, w.y, acc[b]);
                    acc[b] = fmaf(v.z, w.z, acc[b]);
                    acc[b] = fmaf(v.w, w.w, acc[b]);
                }
            }
        }

        // ---- wait for peers' h(t-1) (ACQUIRE), refill foreign 192 cols ----
        if (t) {
            if (j == 0) {
                int it = 0;
                while (__hip_atomic_load(mycnt, __ATOMIC_ACQUIRE, SCOPE_AGENT) < 4 * t
                       && it++ < SPIN_CAP)
                    __builtin_amdgcn_s_sleep(1);
            }
            __syncthreads();
            {
                const int b = j >> 6;
                if ((m >> 4) != g) {
                    const float* src = Hbuf + ((((size_t)((t - 1) & 1)) * 64 + bg) * 4 + b) * 256;
                    const int col = 4 * m;
                    const float a0 = __hip_atomic_load(src + col + 0, __ATOMIC_RELAXED, SCOPE_AGENT);
                    const float a1 = __hip_atomic_load(src + col + 1, __ATOMIC_RELAXED, SCOPE_AGENT);
                    const float a2 = __hip_atomic_load(src + col + 2, __ATOMIC_RELAXED, SCOPE_AGENT);
                    const float a3 = __hip_atomic_load(src + col + 3, __ATOMIC_RELAXED, SCOPE_AGENT);
                    comb[b][col + 0] = a0; comb[b][col + 1] = a1;
                    comb[b][col + 2] = a2; comb[b][col + 3] = a3;
                }
            }
            __syncthreads();
        }

        // ---- phase B: foreign slices; 11 quads regs, 37 quads LDS ----
        #pragma unroll
        for (int qd = RQ_OWN; qd < RQ_REG; ++qd) {
            const float4 w = wR4[qd];
            const int k = kb1 + (qd - RQ_OWN) * 4;
            #pragma unroll
            for (int b = 0; b < NB; ++b) {
                const float4 v = *(const float4*)&comb[b][k];
                acc[b] = fmaf(v.x, w.x, acc[b]);
                acc[b] = fmaf(v.y, w.y, acc[b]);
                acc[b] = fmaf(v.z, w.z, acc[b]);
                acc[b] = fmaf(v.w, w.w, acc[b]);
            }
        }
        #pragma unroll 4
        for (int rr = 0; rr < LQ; ++rr) {
            const int obo = 44 + rr * 4;
            const int k = ((obo >> 6) == 0 ? kb1 : (obo >> 6) == 1 ? kb2 : kb3) + (obo & 63);
            const float4 w = WldsQ[rr][j];
            #pragma unroll
            for (int b = 0; b < NB; ++b) {
                const float4 v = *(const float4*)&comb[b][k];
                acc[b] = fmaf(v.x, w.x, acc[b]);
                acc[b] = fmaf(v.y, w.y, acc[b]);
                acc[b] = fmaf(v.z, w.z, acc[b]);
                acc[b] = fmaf(v.w, w.w, acc[b]);
            }
        }

        // ---- prefetch next step's x-term ----
        float xv = 0.0f;
        const int tt = (t + 1 < Tsz) ? t + 1 : t;
        if constexpr (XPRE) {
            #pragma unroll
            for (int b = 0; b < NB; ++b)
                xpc[b] = xpbase[((size_t)(b0 + b) * Tsz + tt) * 1024];
        } else {
            xv = x[((size_t)(b0 + (j >> 6)) * Tsz + tt) * Isz + m];
        }

        // ---- gate exchange + cell update ----
        #pragma unroll
        for (int b = 0; b < NB; ++b) gat[q][b][m] = acc[b];
        __syncthreads();
        {
            const int b = j >> 6;
            const float gf = gat[0][b][m], gi = gat[1][b][m];
            const float gc = gat[2][b][m], go = gat[3][b][m];
            const float f  = 1.0f / (1.0f + expf(-gf));
            const float ii = 1.0f / (1.0f + expf(-gi));
            const float ch = tanhf(gc);
            const float oo = 1.0f / (1.0f + expf(-go));
            cstate = f * cstate + ii * ch;
            const float h = oo * tanhf(cstate);
            comb[b][g * 64 + m] = h;
            float* dst = Hbuf + ((((size_t)(t & 1)) * 64 + bg) * 4 + b) * 256 + g * 64 + m;
            __hip_atomic_store(dst, h, __ATOMIC_RELAXED, SCOPE_AGENT);
        }
        if constexpr (!XPRE) comb[j >> 6][Hsz + m] = xv;
        __syncthreads();
        if (j == 0)
            __hip_atomic_fetch_add(mycnt, 1, __ATOMIC_RELEASE, SCOPE_AGENT);
    }

    // ---- final projection by wg g==0 of each batch group ----
    if (g == 0) {
        if (j == 0) {
            int it = 0;
            while (__hip_atomic_load(mycnt, __ATOMIC_ACQUIRE, SCOPE_AGENT) < 4 * Tsz
                   && it++ < SPIN_CAP)
                __builtin_amdgcn_s_sleep(1);
        }
        __syncthreads();
        {
            const int b = j >> 6;
            if ((m >> 4) != 0) {
                const float* src = Hbuf + ((((size_t)((Tsz - 1) & 1)) * 64 + bg) * 4 + b) * 256;
                const int col = 4 * m;
                const float a0 = __hip_atomic_load(src + col + 0, __ATOMIC_RELAXED, SCOPE_AGENT);
                const float a1 = __hip_atomic_load(src + col + 1, __ATOMIC_RELAXED, SCOPE_AGENT);
                const float a2 = __hip_atomic_load(src + col + 2, __ATOMIC_RELAXED, SCOPE_AGENT);
                const float a3 = __hip_atomic_load(src + col + 3, __ATOMIC_RELAXED, SCOPE_AGENT);
                comb[b][col + 0] = a0; comb[b][col + 1] = a1;
                comb[b][col + 2] = a2; comb[b][col + 3] = a3;
            }
        }
        __syncthreads();
        if (j < NB * Osz) {
            const int b = j >> 3, o = j & 7;
            float s = b_ho[o];
            #pragma unroll 8
            for (int k2 = 0; k2 < Hsz; ++k2)
                s = fmaf(comb[b][k2], W_ho[k2 * Osz + o], s);
            out[(size_t)(b0 + b) * Osz + o] = s;
        }
    }
}

extern "C" void kernel_launch(void* const* d_in, const int* in_sizes, int n_in,
                              void* d_out, int out_size, void* d_ws, size_t ws_size,
                              hipStream_t stream) {
    const float* xp  = (const float*)d_in[0];
    const float* wf  = (const float*)d_in[1];
    const float* bf  = (const float*)d_in[2];
    const float* wi  = (const float*)d_in[3];
    const float* bi  = (const float*)d_in[4];
    const float* wc  = (const float*)d_in[5];
    const float* bc  = (const float*)d_in[6];
    const float* wo  = (const float*)d_in[7];
    const float* bo  = (const float*)d_in[8];
    const float* who = (const float*)d_in[9];
    const float* bho = (const float*)d_in[10];
    float* outp = (float*)d_out;

    int*   cntp  = (int*)d_ws;                          // flags @ 0
    float* hbufp = (float*)((char*)d_ws + 4096);        // 512 KB h-exchange
    float* xprojp = (float*)((char*)d_ws + (1 << 20));  // 1.07 GB xproj
    const size_t need = (size_t)(1 << 20) + (size_t)Bsz * Tsz * 1024 * sizeof(float);

    hipMemsetAsync(d_ws, 0, 4096, stream);

    if (ws_size >= need) {
        xproj_kernel<<<dim3(Tsz / 32, Bsz, 4), dim3(256), 0, stream>>>(
            xp, wf, bf, wi, bi, wc, bc, wo, bo, xprojp);
        lstm_ws_kernel<true><<<dim3(NG * 64), dim3(256), 0, stream>>>(
            xp, wf, bf, wi, bi, wc, bc, wo, bo, who, bho, outp, cntp, hbufp, xprojp);
    } else {
        lstm_ws_kernel<false><<<dim3(NG * 64), dim3(256), 0, stream>>>(
            xp, wf, bf, wi, bi, wc, bc, wo, bo, who, bho, outp, cntp, hbufp, nullptr);
    }
}